// Round 1
// baseline (7839.355 us; speedup 1.0000x reference)
//
#include <hip/hip_runtime.h>
#include <math.h>

#define T_DIM 256
#define B_DIM 64
#define KDIM 2048   // I*D == H*D
#define TBROWS 16384

constexpr float EPSF = 1e-15f;
constexpr float MAXN = 1.0f - 1e-5f;

__device__ __forceinline__ float atanh_ref(float x) {
  x = fminf(x, 1.0f - EPSF);
  return 0.5f * (log1pf(x + EPSF) - log1pf(EPSF - x));
}

// reduce two values across a 256-thread block; result broadcast to all threads
__device__ __forceinline__ void block_reduce2(float& v0, float& v1, float* lds) {
  #pragma unroll
  for (int off = 32; off > 0; off >>= 1) {
    v0 += __shfl_down(v0, off, 64);
    v1 += __shfl_down(v1, off, 64);
  }
  const int lane = threadIdx.x & 63;
  const int wid  = threadIdx.x >> 6;
  if (lane == 0) { lds[wid * 2] = v0; lds[wid * 2 + 1] = v1; }
  __syncthreads();
  if (threadIdx.x == 0) {
    float s0 = 0.f, s1 = 0.f;
    #pragma unroll
    for (int w = 0; w < 4; ++w) { s0 += lds[w * 2]; s1 += lds[w * 2 + 1]; }
    lds[0] = s0; lds[1] = s1;
  }
  __syncthreads();
  v0 = lds[0]; v1 = lds[1];
  __syncthreads();
}

// ---------------------------------------------------------------------------
// Big GEMM: Mx[r][c] = sum_k (x[r][k]+EPS) * Um[k][c], r = t*64+b,
// x row (t,b) lives at inputs[(b*256 + t)*2048].
// 64x64x16 tile, 256 threads, 4x4 microtile.
// ---------------------------------------------------------------------------
__global__ __launch_bounds__(256) void gemm_ux(const float* __restrict__ inp,
                                               const float* __restrict__ Um,
                                               float* __restrict__ Mx) {
  const int n0 = blockIdx.x * 64;
  const int m0 = blockIdx.y * 64;
  const int t0 = m0 >> 6;  // == blockIdx.y
  __shared__ float As[16][68];
  __shared__ float Bs[16][64];
  const int tid = threadIdx.x;
  const int tx = tid & 15, ty = tid >> 4;
  const int ai = tid >> 2, ak = (tid & 3) * 4;
  const int bk = tid >> 4, bn = (tid & 15) * 4;
  const float* Arow = inp + ((size_t)(ai * T_DIM + t0)) * KDIM;
  float acc[4][4] = {};
  for (int k0 = 0; k0 < KDIM; k0 += 16) {
    float4 av = *(const float4*)(Arow + k0 + ak);
    As[ak + 0][ai] = av.x + EPSF;
    As[ak + 1][ai] = av.y + EPSF;
    As[ak + 2][ai] = av.z + EPSF;
    As[ak + 3][ai] = av.w + EPSF;
    float4 bv = *(const float4*)(Um + (size_t)(k0 + bk) * KDIM + n0 + bn);
    *(float4*)&Bs[bk][bn] = bv;
    __syncthreads();
    #pragma unroll
    for (int k = 0; k < 16; ++k) {
      float4 a4 = *(const float4*)&As[k][ty * 4];
      float4 b4 = *(const float4*)&Bs[k][tx * 4];
      float a[4] = {a4.x, a4.y, a4.z, a4.w};
      float b[4] = {b4.x, b4.y, b4.z, b4.w};
      #pragma unroll
      for (int i = 0; i < 4; ++i)
        #pragma unroll
        for (int j = 0; j < 4; ++j)
          acc[i][j] = fmaf(a[i], b[j], acc[i][j]);
    }
    __syncthreads();
  }
  #pragma unroll
  for (int i = 0; i < 4; ++i) {
    float4 o = make_float4(acc[i][0], acc[i][1], acc[i][2], acc[i][3]);
    *(float4*)(Mx + (size_t)(m0 + ty * 4 + i) * KDIM + n0 + tx * 4) = o;
  }
}

// ---------------------------------------------------------------------------
// Mobius epilogue for the big GEMM (in-place on Mx -> Ux).
// One block per row r = t*64+b.
// ---------------------------------------------------------------------------
__global__ __launch_bounds__(256) void ux_epilogue(const float* __restrict__ inp,
                                                   float* __restrict__ Mx) {
  const int r = blockIdx.x;
  const int t = r >> 6, b = r & 63;
  const float* xrow = inp + ((size_t)(b * T_DIM + t)) * KDIM;
  float* mrow = Mx + (size_t)r * KDIM;
  const int tid = threadIdx.x;
  __shared__ float lds[8];
  float xs2 = 0.f, ms2 = 0.f;
  float m[8];
  #pragma unroll
  for (int j = 0; j < 8; ++j) {
    const int col = tid + j * 256;
    float xv = xrow[col] + EPSF;
    xs2 += xv * xv;
    float mv = mrow[col];
    m[j] = mv;
    ms2 += mv * mv;
  }
  block_reduce2(xs2, ms2, lds);
  float xn = sqrtf(xs2);
  float mnr = sqrtf(ms2);
  float mxn = mnr + EPSF;
  float s = tanhf((mxn / xn) * atanh_ref(xn)) / mxn;
  float na = s * mnr;                       // ||result|| before projection
  float pf = fminf(1.0f, MAXN / fmaxf(na, EPSF));
  float sc = s * pf;
  #pragma unroll
  for (int j = 0; j < 8; ++j)
    mrow[tid + j * 256] = m[j] * sc;
}

// ---------------------------------------------------------------------------
// Generic M=64 GEMM with split-K(8): part[kz][r][c] = sum_{k in slice}
// (A[r*arstride + k] + EPS) * Bm[k][c].   Grid (32, 8), 256 threads.
// ---------------------------------------------------------------------------
__global__ __launch_bounds__(256) void gemm64_splitk(const float* __restrict__ A,
                                                     size_t arstride,
                                                     const float* __restrict__ Bm,
                                                     float* __restrict__ part) {
  const int n0 = blockIdx.x * 64;
  const int kz = blockIdx.y;
  const int kbeg = kz * 256;
  __shared__ float As[16][68];
  __shared__ float Bs[16][64];
  const int tid = threadIdx.x;
  const int tx = tid & 15, ty = tid >> 4;
  const int ai = tid >> 2, ak = (tid & 3) * 4;
  const int bk = tid >> 4, bn = (tid & 15) * 4;
  const float* Arow = A + (size_t)ai * arstride;
  float acc[4][4] = {};
  for (int kt = 0; kt < 16; ++kt) {
    const int k0 = kbeg + kt * 16;
    float4 av = *(const float4*)(Arow + k0 + ak);
    As[ak + 0][ai] = av.x + EPSF;
    As[ak + 1][ai] = av.y + EPSF;
    As[ak + 2][ai] = av.z + EPSF;
    As[ak + 3][ai] = av.w + EPSF;
    float4 bv = *(const float4*)(Bm + (size_t)(k0 + bk) * KDIM + n0 + bn);
    *(float4*)&Bs[bk][bn] = bv;
    __syncthreads();
    #pragma unroll
    for (int k = 0; k < 16; ++k) {
      float4 a4 = *(const float4*)&As[k][ty * 4];
      float4 b4 = *(const float4*)&Bs[k][tx * 4];
      float a[4] = {a4.x, a4.y, a4.z, a4.w};
      float b[4] = {b4.x, b4.y, b4.z, b4.w};
      #pragma unroll
      for (int i = 0; i < 4; ++i)
        #pragma unroll
        for (int j = 0; j < 4; ++j)
          acc[i][j] = fmaf(a[i], b[j], acc[i][j]);
    }
    __syncthreads();
  }
  #pragma unroll
  for (int i = 0; i < 4; ++i) {
    float4 o = make_float4(acc[i][0], acc[i][1], acc[i][2], acc[i][3]);
    *(float4*)(part + ((size_t)kz * 64 + ty * 4 + i) * KDIM + n0 + tx * 4) = o;
  }
}

// ---------------------------------------------------------------------------
// Fallback-path: finish mob_mat_mul from split-K partials into outrows[64][2048]
// ---------------------------------------------------------------------------
__global__ __launch_bounds__(256) void mob_from_parts(const float* __restrict__ part,
                                                      const float* __restrict__ xbase,
                                                      size_t xstride,
                                                      float* __restrict__ outrows) {
  const int b = blockIdx.x;
  const int tid = threadIdx.x;
  __shared__ float lds[8];
  const float* xrow = xbase + (size_t)b * xstride;
  float xs2 = 0.f, ms2 = 0.f;
  float m[8];
  #pragma unroll
  for (int j = 0; j < 8; ++j) {
    const int col = tid + j * 256;
    float xv = xrow[col] + EPSF;
    xs2 += xv * xv;
    float mv = 0.f;
    for (int kz = 0; kz < 8; ++kz)
      mv += part[((size_t)kz * 64 + b) * KDIM + col];
    m[j] = mv;
    ms2 += mv * mv;
  }
  block_reduce2(xs2, ms2, lds);
  float xn = sqrtf(xs2);
  float mnr = sqrtf(ms2);
  float mxn = mnr + EPSF;
  float s = tanhf((mxn / xn) * atanh_ref(xn)) / mxn;
  float na = s * mnr;
  float pf = fminf(1.0f, MAXN / fmaxf(na, EPSF));
  float sc = s * pf;
  #pragma unroll
  for (int j = 0; j < 8; ++j)
    outrows[(size_t)b * KDIM + tid + j * 256] = m[j] * sc;
}

// ---------------------------------------------------------------------------
// One recurrence step: h_new = mob_add(mob_add(mob_mat_mul(Wm,h), ux), bvec).
// part: split-K partials of (h+EPS)@Wm.  uxrows: 64 rows (stride 2048).
// Writes h in place and out[b][t].
// ---------------------------------------------------------------------------
__global__ __launch_bounds__(256) void step_mobius(const float* __restrict__ part,
                                                   float* __restrict__ h,
                                                   const float* __restrict__ uxrows,
                                                   const float* __restrict__ bvec,
                                                   float* __restrict__ out,
                                                   int t) {
  const int b = blockIdx.x;
  const int tid = threadIdx.x;
  __shared__ float lds[8];
  float hv[8], mh[8], uxv[8], bv[8];
  float hn2 = 0.f, mn2 = 0.f;
  #pragma unroll
  for (int j = 0; j < 8; ++j) {
    const int col = tid + j * 256;
    float x = h[(size_t)b * KDIM + col] + EPSF;
    hv[j] = x;
    hn2 += x * x;
    float m = 0.f;
    for (int kz = 0; kz < 8; ++kz)
      m += part[((size_t)kz * 64 + b) * KDIM + col];
    mh[j] = m;
    mn2 += m * m;
    uxv[j] = uxrows[(size_t)b * KDIM + col] + EPSF;  // v = ux + EPS
    bv[j] = bvec[col] + EPSF;                        // v2 = b + EPS
  }
  block_reduce2(hn2, mn2, lds);
  // a = mob_mat_mul(Wm, h)
  float hn = sqrtf(hn2);
  float mnr = sqrtf(mn2);
  float mxn = mnr + EPSF;
  float s = tanhf((mxn / hn) * atanh_ref(hn)) / mxn;
  float n_a = s * mnr;
  float pfa = fminf(1.0f, MAXN / fmaxf(n_a, EPSF));
  float sa = s * pfa;
  float a[8];
  float duv = 0.f, nv = 0.f;
  #pragma unroll
  for (int j = 0; j < 8; ++j) {
    a[j] = sa * mh[j];
    duv += a[j] * uxv[j];
    nv += uxv[j] * uxv[j];
  }
  block_reduce2(duv, nv, lds);
  duv *= 2.0f;
  float na = sa * sa * mn2;  // sum a^2
  float denom = 1.0f + duv + na * nv;
  float c1 = (1.0f + duv + nv) / denom;
  float c2 = (1.0f - na) / denom;
  float r1[8];
  float r1n2 = 0.f, dummy = 0.f;
  #pragma unroll
  for (int j = 0; j < 8; ++j) {
    r1[j] = c1 * a[j] + c2 * uxv[j];
    r1n2 += r1[j] * r1[j];
  }
  block_reduce2(r1n2, dummy, lds);
  float n1 = sqrtf(r1n2);
  float pf1 = fminf(1.0f, MAXN / fmaxf(n1, EPSF));
  // second mob_add with v2 = b + EPS
  float duv2 = 0.f, nv2 = 0.f;
  #pragma unroll
  for (int j = 0; j < 8; ++j) {
    r1[j] *= pf1;
    duv2 += r1[j] * bv[j];
    nv2 += bv[j] * bv[j];
  }
  block_reduce2(duv2, nv2, lds);
  duv2 *= 2.0f;
  float na2 = pf1 * pf1 * r1n2;
  float denom2 = 1.0f + duv2 + na2 * nv2;
  float d1 = (1.0f + duv2 + nv2) / denom2;
  float d2 = (1.0f - na2) / denom2;
  float r2[8];
  float r2n2 = 0.f;
  dummy = 0.f;
  #pragma unroll
  for (int j = 0; j < 8; ++j) {
    r2[j] = d1 * r1[j] + d2 * bv[j];
    r2n2 += r2[j] * r2[j];
  }
  block_reduce2(r2n2, dummy, lds);
  float n2 = sqrtf(r2n2);
  float pf2 = fminf(1.0f, MAXN / fmaxf(n2, EPSF));
  #pragma unroll
  for (int j = 0; j < 8; ++j) {
    const int col = tid + j * 256;
    float vout = r2[j] * pf2;
    h[(size_t)b * KDIM + col] = vout;
    out[((size_t)b * T_DIM + t) * KDIM + col] = vout;
  }
}

extern "C" void kernel_launch(void* const* d_in, const int* in_sizes, int n_in,
                              void* d_out, int out_size, void* d_ws, size_t ws_size,
                              hipStream_t stream) {
  const float* inp  = (const float*)d_in[0];  // (B,T,I,D) = 64x256x2048
  const float* wm   = (const float*)d_in[1];  // (2048,2048)
  const float* um   = (const float*)d_in[2];  // (2048,2048)
  const float* bvec = (const float*)d_in[3];  // (2048)
  float* out = (float*)d_out;
  char* ws = (char*)d_ws;

  const size_t UX_BYTES = (size_t)TBROWS * KDIM * 4;  // 134 MB
  const size_t H_BYTES = (size_t)B_DIM * KDIM * 4;    // 512 KB
  const size_t PART_BYTES = (size_t)8 * B_DIM * KDIM * 4;  // 4 MB
  const bool big = ws_size >= UX_BYTES + H_BYTES + PART_BYTES;

  if (big) {
    float* Ux = (float*)ws;
    float* h = (float*)(ws + UX_BYTES);
    float* part = (float*)(ws + UX_BYTES + H_BYTES);
    hipMemsetAsync(h, 0, H_BYTES, stream);
    gemm_ux<<<dim3(32, 256), 256, 0, stream>>>(inp, um, Ux);
    ux_epilogue<<<TBROWS, 256, 0, stream>>>(inp, Ux);
    for (int t = 0; t < T_DIM; ++t) {
      gemm64_splitk<<<dim3(32, 8), 256, 0, stream>>>(h, (size_t)KDIM, wm, part);
      step_mobius<<<B_DIM, 256, 0, stream>>>(part, h, Ux + (size_t)t * B_DIM * KDIM,
                                             bvec, out, t);
    }
  } else {
    // small-workspace fallback: compute ux per step on the fly
    float* h = (float*)ws;
    float* part = (float*)(ws + H_BYTES);
    float* partU = (float*)(ws + H_BYTES + PART_BYTES);
    float* uxstep = (float*)(ws + H_BYTES + 2 * PART_BYTES);
    hipMemsetAsync(h, 0, H_BYTES, stream);
    for (int t = 0; t < T_DIM; ++t) {
      const float* xt = inp + (size_t)t * KDIM;  // row b at stride 256*2048
      gemm64_splitk<<<dim3(32, 8), 256, 0, stream>>>(xt, (size_t)T_DIM * KDIM, um, partU);
      mob_from_parts<<<B_DIM, 256, 0, stream>>>(partU, xt, (size_t)T_DIM * KDIM, uxstep);
      gemm64_splitk<<<dim3(32, 8), 256, 0, stream>>>(h, (size_t)KDIM, wm, part);
      step_mobius<<<B_DIM, 256, 0, stream>>>(part, h, uxstep, bvec, out, t);
    }
  }
}

// Round 2
// 6420.763 us; speedup vs baseline: 1.2209x; 1.2209x over previous
//
#include <hip/hip_runtime.h>
#include <math.h>

#define T_DIM 256
#define B_DIM 64
#define KDIM 2048   // I*D == H*D
#define TBROWS 16384

constexpr float EPSF = 1e-15f;
constexpr float MAXN = 1.0f - 1e-5f;

typedef short bf16x8 __attribute__((ext_vector_type(8)));
typedef float f32x4 __attribute__((ext_vector_type(4)));

__device__ __forceinline__ float atanh_ref(float x) {
  x = fminf(x, 1.0f - EPSF);
  return 0.5f * (log1pf(x + EPSF) - log1pf(EPSF - x));
}

__device__ __forceinline__ unsigned short f2bf(float x) {
  unsigned int u = __float_as_uint(x);
  unsigned int r = (u + 0x7fffu + ((u >> 16) & 1u)) >> 16;
  return (unsigned short)r;
}
__device__ __forceinline__ float bf2f(unsigned short h) {
  return __uint_as_float(((unsigned int)h) << 16);
}

__device__ __forceinline__ void gload16(const void* g, void* l) {
  __builtin_amdgcn_global_load_lds(
      (const __attribute__((address_space(1))) unsigned int*)g,
      (__attribute__((address_space(3))) unsigned int*)l, 16, 0, 0);
}

// reduce two values across a 256-thread block; result broadcast to all threads
__device__ __forceinline__ void block_reduce2(float& v0, float& v1, float* lds) {
  #pragma unroll
  for (int off = 32; off > 0; off >>= 1) {
    v0 += __shfl_down(v0, off, 64);
    v1 += __shfl_down(v1, off, 64);
  }
  const int lane = threadIdx.x & 63;
  const int wid  = threadIdx.x >> 6;
  if (lane == 0) { lds[wid * 2] = v0; lds[wid * 2 + 1] = v1; }
  __syncthreads();
  if (threadIdx.x == 0) {
    float s0 = 0.f, s1 = 0.f;
    #pragma unroll
    for (int w = 0; w < 4; ++w) { s0 += lds[w * 2]; s1 += lds[w * 2 + 1]; }
    lds[0] = s0; lds[1] = s1;
  }
  __syncthreads();
  v0 = lds[0]; v1 = lds[1];
  __syncthreads();
}

// ---------------------------------------------------------------------------
// Convert inputs to bf16 hi/lo planes, permuting rows (b*256+t) -> (t*64+b).
// One block per input row.
// ---------------------------------------------------------------------------
__global__ __launch_bounds__(256) void convert_a(const float* __restrict__ inp,
                                                 unsigned short* __restrict__ Ah,
                                                 unsigned short* __restrict__ Al) {
  const int i = blockIdx.x;                      // input row = b*256 + t
  const int r = ((i & 255) << 6) + (i >> 8);     // out row = t*64 + b
  const float* src = inp + (size_t)i * KDIM;
  unsigned short* dh = Ah + (size_t)r * KDIM;
  unsigned short* dl = Al + (size_t)r * KDIM;
  const int base = threadIdx.x * 8;
  float4 v0 = *(const float4*)(src + base);
  float4 v1 = *(const float4*)(src + base + 4);
  float f[8] = {v0.x, v0.y, v0.z, v0.w, v1.x, v1.y, v1.z, v1.w};
  unsigned short h[8], l[8];
  #pragma unroll
  for (int j = 0; j < 8; ++j) {
    unsigned short hb = f2bf(f[j]);
    h[j] = hb;
    l[j] = f2bf(f[j] - bf2f(hb));
  }
  *(bf16x8*)(dh + base) = *(bf16x8*)h;
  *(bf16x8*)(dl + base) = *(bf16x8*)l;
}

// ---------------------------------------------------------------------------
// Transpose + convert Um (2048x2048) into B^T bf16 hi/lo: Bt[n][k] = Um[k][n].
// 64x64 tiles, grid (32,32).
// ---------------------------------------------------------------------------
__global__ __launch_bounds__(256) void convert_bt(const float* __restrict__ Um,
                                                  unsigned short* __restrict__ Bh,
                                                  unsigned short* __restrict__ Bl) {
  __shared__ float t[64][65];
  const int k0 = blockIdx.y * 64, nn0 = blockIdx.x * 64;
  const int tid = threadIdx.x;
  #pragma unroll
  for (int j = 0; j < 4; ++j) {
    int idx = tid + j * 256;
    int r = idx >> 4, c4 = (idx & 15) * 4;
    float4 v = *(const float4*)(Um + (size_t)(k0 + r) * KDIM + nn0 + c4);
    t[r][c4 + 0] = v.x; t[r][c4 + 1] = v.y; t[r][c4 + 2] = v.z; t[r][c4 + 3] = v.w;
  }
  __syncthreads();
  #pragma unroll
  for (int j = 0; j < 4; ++j) {
    int idx = tid + j * 256;
    int n = idx >> 4, ks = (idx & 15) * 4;
    unsigned short hh[4], ll[4];
    #pragma unroll
    for (int q = 0; q < 4; ++q) {
      float x = t[ks + q][n];
      unsigned short hb = f2bf(x);
      hh[q] = hb;
      ll[q] = f2bf(x - bf2f(hb));
    }
    *(ushort4*)(Bh + (size_t)(nn0 + n) * KDIM + k0 + ks) = *(ushort4*)hh;
    *(ushort4*)(Bl + (size_t)(nn0 + n) * KDIM + k0 + ks) = *(ushort4*)ll;
  }
}

// ---------------------------------------------------------------------------
// bf16x3-split MFMA GEMM: C[m][n] = sum_k A[m][k]*B[n][k] (B stored as B^T),
// where A ~ Ah+Al, B ~ Bh+Bl; computes hh + hl + lh (drops ll, ~2^-18 rel).
// 128x128 tile, BK=32, 4 waves (2x2), 16x16x32 MFMA, 4x4 frags/wave.
// global_load_lds staging with slot^=(row&3) XOR swizzle.
// ---------------------------------------------------------------------------
__global__ __launch_bounds__(256) void gemm_mfma3(const unsigned short* __restrict__ Ah,
                                                  const unsigned short* __restrict__ Al,
                                                  const unsigned short* __restrict__ Bh,
                                                  const unsigned short* __restrict__ Bl,
                                                  float* __restrict__ C) {
  __shared__ unsigned char LAh[8192], LAl[8192], LBh[8192], LBl[8192];
  const int tid = threadIdx.x;
  const int lane = tid & 63;
  const int w = tid >> 6;
  const int wr = w >> 1, wc = w & 1;
  const int m0 = blockIdx.x * 128;   // m-major grid: same-XCD blocks share B panel
  const int n0 = blockIdx.y * 128;

  f32x4 acc[4][4] = {};

  for (int k0 = 0; k0 < KDIM; k0 += 32) {
    #pragma unroll
    for (int j = 0; j < 2; ++j) {
      int c = j * 256 + tid;
      int row = c >> 2;
      int sp = (c & 3) ^ (row & 3);          // swizzled source slot
      size_t aoff = (size_t)(m0 + row) * KDIM + k0 + sp * 8;
      size_t boff = (size_t)(n0 + row) * KDIM + k0 + sp * 8;
      int ldsb = (j * 256 + w * 64) * 16;    // wave-uniform base; +lane*16 in HW
      gload16(Ah + aoff, LAh + ldsb);
      gload16(Al + aoff, LAl + ldsb);
      gload16(Bh + boff, LBh + ldsb);
      gload16(Bl + boff, LBl + ldsb);
    }
    __syncthreads();
    bf16x8 ah[4], al[4], bh[4], bl[4];
    #pragma unroll
    for (int i = 0; i < 4; ++i) {
      int arow = wr * 64 + i * 16 + (lane & 15);
      int abyte = arow * 64 + (((lane >> 4) ^ (arow & 3)) * 16);
      ah[i] = *(const bf16x8*)(LAh + abyte);
      al[i] = *(const bf16x8*)(LAl + abyte);
      int brow = wc * 64 + i * 16 + (lane & 15);
      int bbyte = brow * 64 + (((lane >> 4) ^ (brow & 3)) * 16);
      bh[i] = *(const bf16x8*)(LBh + bbyte);
      bl[i] = *(const bf16x8*)(LBl + bbyte);
    }
    #pragma unroll
    for (int i = 0; i < 4; ++i)
      #pragma unroll
      for (int jn = 0; jn < 4; ++jn) {
        acc[i][jn] = __builtin_amdgcn_mfma_f32_16x16x32_bf16(ah[i], bh[jn], acc[i][jn], 0, 0, 0);
        acc[i][jn] = __builtin_amdgcn_mfma_f32_16x16x32_bf16(ah[i], bl[jn], acc[i][jn], 0, 0, 0);
        acc[i][jn] = __builtin_amdgcn_mfma_f32_16x16x32_bf16(al[i], bh[jn], acc[i][jn], 0, 0, 0);
      }
    __syncthreads();
  }
  #pragma unroll
  for (int i = 0; i < 4; ++i) {
    int grow = m0 + wr * 64 + i * 16 + ((lane >> 4) << 2);
    #pragma unroll
    for (int jn = 0; jn < 4; ++jn) {
      int gcol = n0 + wc * 64 + jn * 16 + (lane & 15);
      #pragma unroll
      for (int r = 0; r < 4; ++r)
        C[(size_t)(grow + r) * KDIM + gcol] = acc[i][jn][r];
    }
  }
}

// ---------------------------------------------------------------------------
// fp32 fallback big GEMM (used only if workspace too small for bf16 path)
// ---------------------------------------------------------------------------
__global__ __launch_bounds__(256) void gemm_ux(const float* __restrict__ inp,
                                               const float* __restrict__ Um,
                                               float* __restrict__ Mx) {
  const int n0 = blockIdx.x * 64;
  const int m0 = blockIdx.y * 64;
  const int t0 = m0 >> 6;
  __shared__ float As[16][68];
  __shared__ float Bs[16][64];
  const int tid = threadIdx.x;
  const int tx = tid & 15, ty = tid >> 4;
  const int ai = tid >> 2, ak = (tid & 3) * 4;
  const int bk = tid >> 4, bn = (tid & 15) * 4;
  const float* Arow = inp + ((size_t)(ai * T_DIM + t0)) * KDIM;
  float acc[4][4] = {};
  for (int k0 = 0; k0 < KDIM; k0 += 16) {
    float4 av = *(const float4*)(Arow + k0 + ak);
    As[ak + 0][ai] = av.x + EPSF;
    As[ak + 1][ai] = av.y + EPSF;
    As[ak + 2][ai] = av.z + EPSF;
    As[ak + 3][ai] = av.w + EPSF;
    float4 bv = *(const float4*)(Um + (size_t)(k0 + bk) * KDIM + n0 + bn);
    *(float4*)&Bs[bk][bn] = bv;
    __syncthreads();
    #pragma unroll
    for (int k = 0; k < 16; ++k) {
      float4 a4 = *(const float4*)&As[k][ty * 4];
      float4 b4 = *(const float4*)&Bs[k][tx * 4];
      float a[4] = {a4.x, a4.y, a4.z, a4.w};
      float b[4] = {b4.x, b4.y, b4.z, b4.w};
      #pragma unroll
      for (int i = 0; i < 4; ++i)
        #pragma unroll
        for (int j = 0; j < 4; ++j)
          acc[i][j] = fmaf(a[i], b[j], acc[i][j]);
    }
    __syncthreads();
  }
  #pragma unroll
  for (int i = 0; i < 4; ++i) {
    float4 o = make_float4(acc[i][0], acc[i][1], acc[i][2], acc[i][3]);
    *(float4*)(Mx + (size_t)(m0 + ty * 4 + i) * KDIM + n0 + tx * 4) = o;
  }
}

// ---------------------------------------------------------------------------
// Mobius epilogue for the big GEMM (in-place on Mx -> Ux). One block per row.
// ---------------------------------------------------------------------------
__global__ __launch_bounds__(256) void ux_epilogue(const float* __restrict__ inp,
                                                   float* __restrict__ Mx) {
  const int r = blockIdx.x;
  const int t = r >> 6, b = r & 63;
  const float* xrow = inp + ((size_t)(b * T_DIM + t)) * KDIM;
  float* mrow = Mx + (size_t)r * KDIM;
  const int tid = threadIdx.x;
  __shared__ float lds[8];
  float xs2 = 0.f, ms2 = 0.f;
  float m[8];
  #pragma unroll
  for (int j = 0; j < 8; ++j) {
    const int col = tid + j * 256;
    float xv = xrow[col] + EPSF;
    xs2 += xv * xv;
    float mv = mrow[col];
    m[j] = mv;
    ms2 += mv * mv;
  }
  block_reduce2(xs2, ms2, lds);
  float xn = sqrtf(xs2);
  float mnr = sqrtf(ms2);
  float mxn = mnr + EPSF;
  float s = tanhf((mxn / xn) * atanh_ref(xn)) / mxn;
  float na = s * mnr;
  float pf = fminf(1.0f, MAXN / fmaxf(na, EPSF));
  float sc = s * pf;
  #pragma unroll
  for (int j = 0; j < 8; ++j)
    mrow[tid + j * 256] = m[j] * sc;
}

// ---------------------------------------------------------------------------
// Generic M=64 GEMM with split-K(8). Grid (32, 8), 256 threads.
// ---------------------------------------------------------------------------
__global__ __launch_bounds__(256) void gemm64_splitk(const float* __restrict__ A,
                                                     size_t arstride,
                                                     const float* __restrict__ Bm,
                                                     float* __restrict__ part) {
  const int n0 = blockIdx.x * 64;
  const int kz = blockIdx.y;
  const int kbeg = kz * 256;
  __shared__ float As[16][68];
  __shared__ float Bs[16][64];
  const int tid = threadIdx.x;
  const int tx = tid & 15, ty = tid >> 4;
  const int ai = tid >> 2, ak = (tid & 3) * 4;
  const int bk = tid >> 4, bn = (tid & 15) * 4;
  const float* Arow = A + (size_t)ai * arstride;
  float acc[4][4] = {};
  for (int kt = 0; kt < 16; ++kt) {
    const int k0 = kbeg + kt * 16;
    float4 av = *(const float4*)(Arow + k0 + ak);
    As[ak + 0][ai] = av.x + EPSF;
    As[ak + 1][ai] = av.y + EPSF;
    As[ak + 2][ai] = av.z + EPSF;
    As[ak + 3][ai] = av.w + EPSF;
    float4 bv = *(const float4*)(Bm + (size_t)(k0 + bk) * KDIM + n0 + bn);
    *(float4*)&Bs[bk][bn] = bv;
    __syncthreads();
    #pragma unroll
    for (int k = 0; k < 16; ++k) {
      float4 a4 = *(const float4*)&As[k][ty * 4];
      float4 b4 = *(const float4*)&Bs[k][tx * 4];
      float a[4] = {a4.x, a4.y, a4.z, a4.w};
      float b[4] = {b4.x, b4.y, b4.z, b4.w};
      #pragma unroll
      for (int i = 0; i < 4; ++i)
        #pragma unroll
        for (int j = 0; j < 4; ++j)
          acc[i][j] = fmaf(a[i], b[j], acc[i][j]);
    }
    __syncthreads();
  }
  #pragma unroll
  for (int i = 0; i < 4; ++i) {
    float4 o = make_float4(acc[i][0], acc[i][1], acc[i][2], acc[i][3]);
    *(float4*)(part + ((size_t)kz * 64 + ty * 4 + i) * KDIM + n0 + tx * 4) = o;
  }
}

// ---------------------------------------------------------------------------
// Fallback-path: finish mob_mat_mul from split-K partials
// ---------------------------------------------------------------------------
__global__ __launch_bounds__(256) void mob_from_parts(const float* __restrict__ part,
                                                      const float* __restrict__ xbase,
                                                      size_t xstride,
                                                      float* __restrict__ outrows) {
  const int b = blockIdx.x;
  const int tid = threadIdx.x;
  __shared__ float lds[8];
  const float* xrow = xbase + (size_t)b * xstride;
  float xs2 = 0.f, ms2 = 0.f;
  float m[8];
  #pragma unroll
  for (int j = 0; j < 8; ++j) {
    const int col = tid + j * 256;
    float xv = xrow[col] + EPSF;
    xs2 += xv * xv;
    float mv = 0.f;
    for (int kz = 0; kz < 8; ++kz)
      mv += part[((size_t)kz * 64 + b) * KDIM + col];
    m[j] = mv;
    ms2 += mv * mv;
  }
  block_reduce2(xs2, ms2, lds);
  float xn = sqrtf(xs2);
  float mnr = sqrtf(ms2);
  float mxn = mnr + EPSF;
  float s = tanhf((mxn / xn) * atanh_ref(xn)) / mxn;
  float na = s * mnr;
  float pf = fminf(1.0f, MAXN / fmaxf(na, EPSF));
  float sc = s * pf;
  #pragma unroll
  for (int j = 0; j < 8; ++j)
    outrows[(size_t)b * KDIM + tid + j * 256] = m[j] * sc;
}

// ---------------------------------------------------------------------------
// One recurrence step: h_new = mob_add(mob_add(mob_mat_mul(Wm,h), ux), bvec).
// ---------------------------------------------------------------------------
__global__ __launch_bounds__(256) void step_mobius(const float* __restrict__ part,
                                                   float* __restrict__ h,
                                                   const float* __restrict__ uxrows,
                                                   const float* __restrict__ bvec,
                                                   float* __restrict__ out,
                                                   int t) {
  const int b = blockIdx.x;
  const int tid = threadIdx.x;
  __shared__ float lds[8];
  float mh[8], uxv[8], bv[8];
  float hn2 = 0.f, mn2 = 0.f;
  #pragma unroll
  for (int j = 0; j < 8; ++j) {
    const int col = tid + j * 256;
    float x = h[(size_t)b * KDIM + col] + EPSF;
    hn2 += x * x;
    float m = 0.f;
    for (int kz = 0; kz < 8; ++kz)
      m += part[((size_t)kz * 64 + b) * KDIM + col];
    mh[j] = m;
    mn2 += m * m;
    uxv[j] = uxrows[(size_t)b * KDIM + col] + EPSF;
    bv[j] = bvec[col] + EPSF;
  }
  block_reduce2(hn2, mn2, lds);
  float hn = sqrtf(hn2);
  float mnr = sqrtf(mn2);
  float mxn = mnr + EPSF;
  float s = tanhf((mxn / hn) * atanh_ref(hn)) / mxn;
  float n_a = s * mnr;
  float pfa = fminf(1.0f, MAXN / fmaxf(n_a, EPSF));
  float sa = s * pfa;
  float a[8];
  float duv = 0.f, nv = 0.f;
  #pragma unroll
  for (int j = 0; j < 8; ++j) {
    a[j] = sa * mh[j];
    duv += a[j] * uxv[j];
    nv += uxv[j] * uxv[j];
  }
  block_reduce2(duv, nv, lds);
  duv *= 2.0f;
  float na = sa * sa * mn2;
  float denom = 1.0f + duv + na * nv;
  float c1 = (1.0f + duv + nv) / denom;
  float c2 = (1.0f - na) / denom;
  float r1[8];
  float r1n2 = 0.f, dummy = 0.f;
  #pragma unroll
  for (int j = 0; j < 8; ++j) {
    r1[j] = c1 * a[j] + c2 * uxv[j];
    r1n2 += r1[j] * r1[j];
  }
  block_reduce2(r1n2, dummy, lds);
  float n1 = sqrtf(r1n2);
  float pf1 = fminf(1.0f, MAXN / fmaxf(n1, EPSF));
  float duv2 = 0.f, nv2 = 0.f;
  #pragma unroll
  for (int j = 0; j < 8; ++j) {
    r1[j] *= pf1;
    duv2 += r1[j] * bv[j];
    nv2 += bv[j] * bv[j];
  }
  block_reduce2(duv2, nv2, lds);
  duv2 *= 2.0f;
  float na2 = pf1 * pf1 * r1n2;
  float denom2 = 1.0f + duv2 + na2 * nv2;
  float d1 = (1.0f + duv2 + nv2) / denom2;
  float d2 = (1.0f - na2) / denom2;
  float r2[8];
  float r2n2 = 0.f;
  dummy = 0.f;
  #pragma unroll
  for (int j = 0; j < 8; ++j) {
    r2[j] = d1 * r1[j] + d2 * bv[j];
    r2n2 += r2[j] * r2[j];
  }
  block_reduce2(r2n2, dummy, lds);
  float n2 = sqrtf(r2n2);
  float pf2 = fminf(1.0f, MAXN / fmaxf(n2, EPSF));
  #pragma unroll
  for (int j = 0; j < 8; ++j) {
    const int col = tid + j * 256;
    float vout = r2[j] * pf2;
    h[(size_t)b * KDIM + col] = vout;
    out[((size_t)b * T_DIM + t) * KDIM + col] = vout;
  }
}

extern "C" void kernel_launch(void* const* d_in, const int* in_sizes, int n_in,
                              void* d_out, int out_size, void* d_ws, size_t ws_size,
                              hipStream_t stream) {
  const float* inp  = (const float*)d_in[0];  // (B,T,I,D) = 64x256x2048
  const float* wm   = (const float*)d_in[1];  // (2048,2048)
  const float* um   = (const float*)d_in[2];  // (2048,2048)
  const float* bvec = (const float*)d_in[3];  // (2048)
  float* out = (float*)d_out;
  char* ws = (char*)d_ws;

  const size_t UX_BYTES = (size_t)TBROWS * KDIM * 4;       // 134.2 MB
  const size_t AHL_BYTES = (size_t)TBROWS * KDIM * 2;      // 67.1 MB each
  const size_t BT_BYTES = (size_t)KDIM * KDIM * 2;         // 8.4 MB each
  const size_t H_BYTES = (size_t)B_DIM * KDIM * 4;         // 512 KB
  const size_t PART_BYTES = (size_t)8 * B_DIM * KDIM * 4;  // 4 MB
  const size_t MFMA_NEED = UX_BYTES + 2 * AHL_BYTES + 2 * BT_BYTES + H_BYTES + PART_BYTES;
  const size_t FP32_NEED = UX_BYTES + H_BYTES + PART_BYTES;

  if (ws_size >= MFMA_NEED) {
    float* Ux = (float*)ws;
    unsigned short* Ah = (unsigned short*)(ws + UX_BYTES);
    unsigned short* Al = (unsigned short*)(ws + UX_BYTES + AHL_BYTES);
    unsigned short* Bh = (unsigned short*)(ws + UX_BYTES + 2 * AHL_BYTES);
    unsigned short* Bl = (unsigned short*)(ws + UX_BYTES + 2 * AHL_BYTES + BT_BYTES);
    float* h = (float*)(ws + UX_BYTES + 2 * AHL_BYTES + 2 * BT_BYTES);
    float* part = (float*)(ws + UX_BYTES + 2 * AHL_BYTES + 2 * BT_BYTES + H_BYTES);
    hipMemsetAsync(h, 0, H_BYTES, stream);
    convert_a<<<TBROWS, 256, 0, stream>>>(inp, Ah, Al);
    convert_bt<<<dim3(32, 32), 256, 0, stream>>>(um, Bh, Bl);
    gemm_mfma3<<<dim3(128, 16), 256, 0, stream>>>(Ah, Al, Bh, Bl, Ux);
    ux_epilogue<<<TBROWS, 256, 0, stream>>>(inp, Ux);
    for (int t = 0; t < T_DIM; ++t) {
      gemm64_splitk<<<dim3(32, 8), 256, 0, stream>>>(h, (size_t)KDIM, wm, part);
      step_mobius<<<B_DIM, 256, 0, stream>>>(part, h, Ux + (size_t)t * B_DIM * KDIM,
                                             bvec, out, t);
    }
  } else if (ws_size >= FP32_NEED) {
    float* Ux = (float*)ws;
    float* h = (float*)(ws + UX_BYTES);
    float* part = (float*)(ws + UX_BYTES + H_BYTES);
    hipMemsetAsync(h, 0, H_BYTES, stream);
    gemm_ux<<<dim3(32, 256), 256, 0, stream>>>(inp, um, Ux);
    ux_epilogue<<<TBROWS, 256, 0, stream>>>(inp, Ux);
    for (int t = 0; t < T_DIM; ++t) {
      gemm64_splitk<<<dim3(32, 8), 256, 0, stream>>>(h, (size_t)KDIM, wm, part);
      step_mobius<<<B_DIM, 256, 0, stream>>>(part, h, Ux + (size_t)t * B_DIM * KDIM,
                                             bvec, out, t);
    }
  } else {
    float* h = (float*)ws;
    float* part = (float*)(ws + H_BYTES);
    float* partU = (float*)(ws + H_BYTES + PART_BYTES);
    float* uxstep = (float*)(ws + H_BYTES + 2 * PART_BYTES);
    hipMemsetAsync(h, 0, H_BYTES, stream);
    for (int t = 0; t < T_DIM; ++t) {
      const float* xt = inp + (size_t)t * KDIM;
      gemm64_splitk<<<dim3(32, 8), 256, 0, stream>>>(xt, (size_t)T_DIM * KDIM, um, partU);
      mob_from_parts<<<B_DIM, 256, 0, stream>>>(partU, xt, (size_t)T_DIM * KDIM, uxstep);
      gemm64_splitk<<<dim3(32, 8), 256, 0, stream>>>(h, (size_t)KDIM, wm, part);
      step_mobius<<<B_DIM, 256, 0, stream>>>(part, h, uxstep, bvec, out, t);
    }
  }
}